// Round 1
// baseline (5370.720 us; speedup 1.0000x reference)
//
#include <hip/hip_runtime.h>

// SparseRNN: out = COO_spmm(rows, cols, vals, inp) + bias
// N = 100000, D = 128, nnz = 2*N*32 + N = 6,500,000
//
// Round 1 baseline: wave-per-edge atomic scatter.
//  - init_out writes bias into out (harness poisons d_out with 0xAA each call)
//  - edge_scatter: each 64-lane wave owns one edge per loop iteration.
//    lane l handles features [2l, 2l+1] (float2): 64 lanes x 8 B = 512 B
//    perfectly-coalesced gather of inp[col,:], then 2 f32 atomicAdds into
//    out[row,:]. Atomics are device-scope by default (guide G12).

#define FEAT 128
#define FEAT2 (FEAT / 2)   // float2 elements per row
#define FEAT4 (FEAT / 4)   // float4 elements per row

__global__ void init_out_kernel(float* __restrict__ out,
                                const float* __restrict__ bias,
                                int n_rows) {
    // one float4 per thread, grid-stride
    int total = n_rows * FEAT4;
    for (int idx = blockIdx.x * blockDim.x + threadIdx.x; idx < total;
         idx += gridDim.x * blockDim.x) {
        int row = idx >> 5;              // idx / (128/4)
        float b = bias[row];
        reinterpret_cast<float4*>(out)[idx] = make_float4(b, b, b, b);
    }
}

__global__ void edge_scatter_kernel(const float* __restrict__ inp,
                                    const int* __restrict__ rows,
                                    const int* __restrict__ cols,
                                    const float* __restrict__ vals,
                                    float* __restrict__ out,
                                    int nnz) {
    const int lane   = threadIdx.x & 63;
    const int wave   = (blockIdx.x * blockDim.x + threadIdx.x) >> 6;
    const int nwaves = (gridDim.x * blockDim.x) >> 6;

    for (int e = wave; e < nnz; e += nwaves) {
        // wave-uniform edge metadata (hardware broadcasts same-address loads)
        const int   r = rows[e];
        const int   c = cols[e];
        const float v = vals[e];

        // coalesced 512 B gather of inp[c, :]
        const float2 g =
            reinterpret_cast<const float2*>(inp + (size_t)c * FEAT)[lane];

        float* o = out + (size_t)r * FEAT + 2 * lane;
        atomicAdd(o + 0, v * g.x);
        atomicAdd(o + 1, v * g.y);
    }
}

extern "C" void kernel_launch(void* const* d_in, const int* in_sizes, int n_in,
                              void* d_out, int out_size, void* d_ws, size_t ws_size,
                              hipStream_t stream) {
    const float* inp  = (const float*)d_in[0];
    const int*   rows = (const int*)d_in[1];
    const int*   cols = (const int*)d_in[2];
    const float* vals = (const float*)d_in[3];
    const float* bias = (const float*)d_in[4];
    float*       out  = (float*)d_out;

    const int nnz    = in_sizes[1];      // rows array length = E + N
    const int n_rows = in_sizes[4];      // bias length = N

    // init: N*32 float4 stores = 3.2M; 2048 blocks x 256 thr grid-stride
    init_out_kernel<<<2048, 256, 0, stream>>>(out, bias, n_rows);

    // scatter: 8192 blocks x 256 thr = 32768 waves, ~198 edges each
    edge_scatter_kernel<<<8192, 256, 0, stream>>>(inp, rows, cols, vals, out, nnz);
}

// Round 2
// 1341.342 us; speedup vs baseline: 4.0040x; 4.0040x over previous
//
#include <hip/hip_runtime.h>

// SparseRNN: out = COO_spmm(rows, cols, vals, inp) + bias
// N = 100000, D = 128, nnz = 6,500,000
//
// Round 2: kill the 832M float atomics (R1: WRITE_SIZE showed 1 KB of HBM
// RMW traffic per edge -> 8.5 GB, 5.25 ms). Per-call CSR build in ws:
//   1. zero counts            (int[N])
//   2. histogram rows         (6.5M int atomics into 400 KB -> cache-resident)
//   3. scan -> row_start[N+1] (block sums, scan partials, chunk scans)
//   4. scatter (col,val) 8B records into row buckets (int atomic cursor)
//   5. gather: wave-per-row, register accumulation, ONE write of out[row,:]
// Float atomics: zero. Out write traffic: 51 MB instead of 6.6 GB.

#define N_FEAT 128

constexpr int SCAN_CHUNK   = 1024;  // counts per scan block
constexpr int SCAN_THREADS = 256;   // 4 counts per thread (int4)

// ---------------------------------------------------------------- phase 1
__global__ void zero_kernel(int* __restrict__ p, int n) {
    int i = blockIdx.x * blockDim.x + threadIdx.x;
    if (i < n) p[i] = 0;
}

// ---------------------------------------------------------------- phase 2
__global__ void hist_kernel(const int* __restrict__ rows, int nnz,
                            int* __restrict__ counts) {
    int e = blockIdx.x * blockDim.x + threadIdx.x;
    if (e < nnz) atomicAdd(&counts[rows[e]], 1);
}

// ---------------------------------------------------------------- phase 3a
// partial[b] = sum of counts[b*1024 .. b*1024+1023]
__global__ void block_sum_kernel(const int* __restrict__ counts, int n,
                                 int* __restrict__ partials) {
    __shared__ int lds[SCAN_THREADS];
    const int t = threadIdx.x;
    const int g = blockIdx.x * SCAN_CHUNK + t * 4;
    int s = 0;
    if (g + 3 < n) {
        int4 c = reinterpret_cast<const int4*>(counts)[ (blockIdx.x * SCAN_CHUNK) / 4 + t ];
        s = c.x + c.y + c.z + c.w;
    } else {
        for (int j = 0; j < 4; ++j) if (g + j < n) s += counts[g + j];
    }
    lds[t] = s;
    __syncthreads();
    for (int off = SCAN_THREADS / 2; off > 0; off >>= 1) {
        if (t < off) lds[t] += lds[t + off];
        __syncthreads();
    }
    if (t == 0) partials[blockIdx.x] = lds[0];
}

// ---------------------------------------------------------------- phase 3b
// single block: exclusive scan of nchunks partials -> chunk_base
__global__ void scan_partials_kernel(const int* __restrict__ partials,
                                     int* __restrict__ chunk_base, int nchunks) {
    __shared__ int lds[4096];
    for (int i = threadIdx.x; i < nchunks; i += blockDim.x) lds[i] = partials[i];
    __syncthreads();
    if (threadIdx.x == 0) {
        int run = 0;
        for (int i = 0; i < nchunks; ++i) { int v = lds[i]; lds[i] = run; run += v; }
    }
    __syncthreads();
    for (int i = threadIdx.x; i < nchunks; i += blockDim.x) chunk_base[i] = lds[i];
}

// ---------------------------------------------------------------- phase 3c
// exclusive scan within each 1024-chunk + chunk_base -> row_start, cursor
__global__ void scan_chunks_kernel(const int* __restrict__ counts, int n,
                                   const int* __restrict__ chunk_base,
                                   int* __restrict__ row_start,
                                   int* __restrict__ cursor, int nnz) {
    __shared__ int lds[SCAN_THREADS];
    const int t = threadIdx.x;
    const int g = blockIdx.x * SCAN_CHUNK + t * 4;
    int4 c = make_int4(0, 0, 0, 0);
    if (g + 3 < n) {
        c = reinterpret_cast<const int4*>(counts)[ (blockIdx.x * SCAN_CHUNK) / 4 + t ];
    } else {
        if (g + 0 < n) c.x = counts[g + 0];
        if (g + 1 < n) c.y = counts[g + 1];
        if (g + 2 < n) c.z = counts[g + 2];
        if (g + 3 < n) c.w = counts[g + 3];
    }
    const int s3 = c.x + c.y + c.z + c.w;  // thread-local total
    lds[t] = s3;
    __syncthreads();
    // Hillis-Steele inclusive scan over 256 thread totals
    for (int off = 1; off < SCAN_THREADS; off <<= 1) {
        int v = (t >= off) ? lds[t - off] : 0;
        __syncthreads();
        lds[t] += v;
        __syncthreads();
    }
    const int excl = lds[t] - s3;  // exclusive prefix of this thread
    int base = chunk_base[blockIdx.x] + excl;
    int o0 = base;
    int o1 = o0 + c.x;
    int o2 = o1 + c.y;
    int o3 = o2 + c.z;
    if (g + 0 < n) { row_start[g + 0] = o0; cursor[g + 0] = o0; }
    if (g + 1 < n) { row_start[g + 1] = o1; cursor[g + 1] = o1; }
    if (g + 2 < n) { row_start[g + 2] = o2; cursor[g + 2] = o2; }
    if (g + 3 < n) { row_start[g + 3] = o3; cursor[g + 3] = o3; }
    if (blockIdx.x == 0 && t == 0) row_start[n] = nnz;
}

// ---------------------------------------------------------------- phase 4
__global__ void scatter_kernel(const int* __restrict__ rows,
                               const int* __restrict__ cols,
                               const float* __restrict__ vals, int nnz,
                               int* __restrict__ cursor,
                               int2* __restrict__ records) {
    int e = blockIdx.x * blockDim.x + threadIdx.x;
    if (e >= nnz) return;
    int r = rows[e];
    int pos = atomicAdd(&cursor[r], 1);
    records[pos] = make_int2(cols[e], __float_as_int(vals[e]));
}

// ---------------------------------------------------------------- phase 5
// one 64-lane wave per row; lane l owns features [2l, 2l+1]
__global__ void gather_kernel(const float* __restrict__ inp,
                              const int2* __restrict__ records,
                              const int* __restrict__ row_start,
                              const float* __restrict__ bias,
                              float* __restrict__ out, int n_rows) {
    const int lane = threadIdx.x & 63;
    const int row  = (blockIdx.x * blockDim.x + threadIdx.x) >> 6;
    if (row >= n_rows) return;

    const int start = row_start[row];
    const int end   = row_start[row + 1];

    float ax = 0.f, ay = 0.f;
    int i = start;
    for (; i + 1 < end; i += 2) {
        int2 r0 = records[i];
        int2 r1 = records[i + 1];
        float2 g0 = reinterpret_cast<const float2*>(inp + (size_t)r0.x * N_FEAT)[lane];
        float2 g1 = reinterpret_cast<const float2*>(inp + (size_t)r1.x * N_FEAT)[lane];
        float v0 = __int_as_float(r0.y);
        float v1 = __int_as_float(r1.y);
        ax = fmaf(v0, g0.x, ax);
        ay = fmaf(v0, g0.y, ay);
        ax = fmaf(v1, g1.x, ax);
        ay = fmaf(v1, g1.y, ay);
    }
    if (i < end) {
        int2 r0 = records[i];
        float2 g0 = reinterpret_cast<const float2*>(inp + (size_t)r0.x * N_FEAT)[lane];
        float v0 = __int_as_float(r0.y);
        ax = fmaf(v0, g0.x, ax);
        ay = fmaf(v0, g0.y, ay);
    }
    const float b = bias[row];
    reinterpret_cast<float2*>(out + (size_t)row * N_FEAT)[lane] =
        make_float2(ax + b, ay + b);
}

// ----------------------------------------------------------------
extern "C" void kernel_launch(void* const* d_in, const int* in_sizes, int n_in,
                              void* d_out, int out_size, void* d_ws, size_t ws_size,
                              hipStream_t stream) {
    const float* inp  = (const float*)d_in[0];
    const int*   rows = (const int*)d_in[1];
    const int*   cols = (const int*)d_in[2];
    const float* vals = (const float*)d_in[3];
    const float* bias = (const float*)d_in[4];
    float*       out  = (float*)d_out;

    const int nnz    = in_sizes[1];   // E + N
    const int n_rows = in_sizes[4];   // N
    const int nchunks = (n_rows + SCAN_CHUNK - 1) / SCAN_CHUNK;

    // workspace layout (records first for 16B alignment)
    char* ws = (char*)d_ws;
    int2* records    = (int2*)ws;                       ws += (size_t)nnz * sizeof(int2);
    int*  counts     = (int*)ws;                        ws += (size_t)(n_rows + 4) * sizeof(int);
    int*  cursor     = (int*)ws;                        ws += (size_t)(n_rows + 4) * sizeof(int);
    int*  row_start  = (int*)ws;                        ws += (size_t)(n_rows + 4) * sizeof(int);
    int*  partials   = (int*)ws;                        ws += (size_t)nchunks * sizeof(int);
    int*  chunk_base = (int*)ws;

    const int ethreads = 256;
    const int eblocks  = (nnz + ethreads - 1) / ethreads;

    zero_kernel<<<(n_rows + 255) / 256, 256, 0, stream>>>(counts, n_rows);
    hist_kernel<<<eblocks, ethreads, 0, stream>>>(rows, nnz, counts);
    block_sum_kernel<<<nchunks, SCAN_THREADS, 0, stream>>>(counts, n_rows, partials);
    scan_partials_kernel<<<1, 256, 0, stream>>>(partials, chunk_base, nchunks);
    scan_chunks_kernel<<<nchunks, SCAN_THREADS, 0, stream>>>(counts, n_rows, chunk_base,
                                                             row_start, cursor, nnz);
    scatter_kernel<<<eblocks, ethreads, 0, stream>>>(rows, cols, vals, nnz, cursor, records);

    // gather: one wave per row, 4 waves per 256-thread block
    const int gblocks = (n_rows + 3) / 4;
    gather_kernel<<<gblocks, 256, 0, stream>>>(inp, records, row_start, bias, out, n_rows);
}